// Round 1
// baseline (1497.042 us; speedup 1.0000x reference)
//
#include <hip/hip_runtime.h>
#include <hip/hip_bf16.h>
#include <stdint.h>

#define NS 32768
#define NXD 64
#define KD 16
#define ED 32
#define DYD 32

typedef __attribute__((ext_vector_type(8))) short short8;
typedef __attribute__((ext_vector_type(4))) float f32x4;

__device__ __forceinline__ void gl_lds16(const void* g, void* s) {
  __builtin_amdgcn_global_load_lds(
      (const __attribute__((address_space(1))) void*)(uintptr_t)g,
      (__attribute__((address_space(3))) void*)(uint32_t)(uintptr_t)s,
      16, 0, 0);
}

// ---------------------------------------------------------------- K0: W12T
// W12T[col=o*64+i][ke=k*32+e] = W1[k,i,e] * W2[k,e,o]   (4096 x 512, bf16)
__global__ __launch_bounds__(256) void prep_w12(
    const float* __restrict__ W1, const float* __restrict__ W2,
    __hip_bfloat16* __restrict__ W12T) {
  int idx = blockIdx.x * 256 + threadIdx.x;        // 0 .. 2M-1
  int col = idx >> 9;
  int ke  = idx & 511;
  int o = col >> 6, i = col & 63;
  int k = ke >> 5,  e = ke & 31;
  float v = W1[k * 2048 + i * 32 + e] * W2[k * 2048 + e * 64 + o];
  W12T[idx] = __float2bfloat16(v);
}

// --------------------------------------------------------------- K1: branch
// per sample: y_norm -> weights (softplus) -> wts[n][16]
//             bias net -> zout[n][o] = x + bias + w@b2
__global__ __launch_bounds__(256) void branch_kernel(
    const float* __restrict__ x, const float* __restrict__ y,
    const float* __restrict__ b2,
    const float* __restrict__ Wb1, const float* __restrict__ bb1,
    const float* __restrict__ Wb2, const float* __restrict__ bb2,
    const float* __restrict__ Wc1, const float* __restrict__ bc1,
    const float* __restrict__ Wc2, const float* __restrict__ bc2,
    const float* __restrict__ meanp, const float* __restrict__ varp,
    float* __restrict__ wts, float* __restrict__ zout) {
  int n = blockIdx.x * 256 + threadIdx.x;
  float yn[DYD];
#pragma unroll
  for (int d = 0; d < DYD; d++) {
    float t = (y[n * DYD + d] - meanp[d]) / sqrtf(varp[d]);
    yn[d] = fminf(fmaxf(t, -10.f), 10.f);
  }
  float t1[64];
#pragma unroll
  for (int u = 0; u < 64; u++) {
    float a = bb1[u];
#pragma unroll
    for (int d = 0; d < DYD; d++) a += yn[d] * Wb1[d * 64 + u];
    t1[u] = fmaxf(a, 0.f);
  }
  float w[KD];
#pragma unroll
  for (int k = 0; k < KD; k++) {
    float a = bb2[k];
#pragma unroll
    for (int u = 0; u < 64; u++) a += t1[u] * Wb2[u * KD + k];
    w[k] = (a > 20.f) ? a : log1pf(expf(a));
    wts[n * KD + k] = w[k];
  }
  float t2[16];
#pragma unroll
  for (int j = 0; j < 16; j++) {
    float a = bc1[j];
#pragma unroll
    for (int d = 0; d < DYD; d++) a += yn[d] * Wc1[d * 16 + j];
    t2[j] = fmaxf(a, 0.f);
  }
#pragma unroll
  for (int o = 0; o < NXD; o++) {
    float a = bc2[o] + x[n * NXD + o];
#pragma unroll
    for (int j = 0; j < 16; j++) a += t2[j] * Wc2[j * 64 + o];
#pragma unroll
    for (int k = 0; k < KD; k++) a += w[k] * b2[k * 64 + o];
    zout[n * NXD + o] = a;
  }
}

// ----------------------------------------------------------------- K2: MoE
// 8 samples/block. h = tanh(x@W1+b1); M=w(1-h^2) -> bf16 ws (GEMM A);
// P=w*h in LDS; z += P @ W2.
__global__ __launch_bounds__(256) void moe_kernel(
    const float* __restrict__ x, const float* __restrict__ W1,
    const float* __restrict__ b1, const float* __restrict__ W2,
    const float* __restrict__ wts,
    __hip_bfloat16* __restrict__ Mb, float* __restrict__ zout) {
  __shared__ __align__(16) float xs[8 * 64];
  __shared__ float wl[8 * 16];
  __shared__ float Pl[8 * 512];
  int t = threadIdx.x;
  int n0 = blockIdx.x * 8;
  xs[t] = x[(size_t)n0 * 64 + t];
  xs[t + 256] = x[(size_t)n0 * 64 + t + 256];
  if (t < 128) wl[t] = wts[n0 * 16 + t];
  __syncthreads();

  int s = t >> 5, e = t & 31;
  float xv[64];
#pragma unroll
  for (int i = 0; i < 64; i++) xv[i] = xs[s * 64 + i];

  for (int k = 0; k < KD; k++) {
    float pre = b1[k * 32 + e];
    const float* w1p = &W1[k * 2048 + e];
#pragma unroll
    for (int i = 0; i < 64; i++) pre += xv[i] * w1p[i * 32];
    float hh = tanhf(pre);
    float wk = wl[s * 16 + k];
    Mb[(size_t)(n0 + s) * 512 + k * 32 + e] = __float2bfloat16(wk * (1.f - hh * hh));
    Pl[s * 512 + k * 32 + e] = wk * hh;
  }
  __syncthreads();

  int o2 = t & 31;  // handles columns 2*o2, 2*o2+1
  const float* pp = &Pl[s * 512];
  float za = 0.f, zb_ = 0.f;
#pragma unroll 8
  for (int ke = 0; ke < 512; ke++) {
    float p = pp[ke];
    const float2 wv = ((const float2*)(W2 + ke * 64))[o2];
    za += p * wv.x;
    zb_ += p * wv.y;
  }
  float2* zp = (float2*)(zout + (size_t)(n0 + s) * 64 + o2 * 2);
  float2 zold = *zp;
  zold.x += za;
  zold.y += zb_;
  *zp = zold;
}

// ---------------------------------------------------------------- K3: GEMM
// C[32768][4096] = A[32768][512] * B^T, B = W12T[4096][512]; C += I on col%65==0
#define BM 128
#define BN 128
#define BK 32
__global__ __launch_bounds__(256) void jac_gemm(
    const __hip_bfloat16* __restrict__ Abf, const __hip_bfloat16* __restrict__ Bbf,
    float* __restrict__ C) {
  __shared__ __align__(16) short As[BM * BK];  // [row][k], 8 KB
  __shared__ __align__(16) short Bs[BN * BK];  // [col][k], 8 KB

  const int tid = threadIdx.x;
  const int wave = tid >> 6;
  const int lane = tid & 63;
  const int row0 = blockIdx.y * BM;
  const int col0 = blockIdx.x * BN;

  // staging: wave w, round r covers LDS bytes [w*2048 + r*1024 + lane*16)
  const int srow = wave * 32 + (lane >> 2);  // +16 for round 1
  const int skc = (lane & 3) * 8;            // k-element offset

  const short* Ag = (const short*)Abf;
  const short* Bg = (const short*)Bbf;

  f32x4 acc[4][4];
#pragma unroll
  for (int i = 0; i < 4; i++)
#pragma unroll
    for (int j = 0; j < 4; j++) acc[i][j] = (f32x4){0.f, 0.f, 0.f, 0.f};

  const int wm = wave >> 1, wn = wave & 1;
  const int lr = lane & 15;
  const int quad = lane >> 4;

  for (int k0 = 0; k0 < 512; k0 += BK) {
    const short* gA0 = Ag + (size_t)(row0 + srow) * 512 + k0 + skc;
    const short* gB0 = Bg + (size_t)(col0 + srow) * 512 + k0 + skc;
    gl_lds16(gA0, &As[srow * 32 + skc]);
    gl_lds16(gA0 + 16 * 512, &As[(srow + 16) * 32 + skc]);
    gl_lds16(gB0, &Bs[srow * 32 + skc]);
    gl_lds16(gB0 + 16 * 512, &Bs[(srow + 16) * 32 + skc]);
    __syncthreads();  // compiler drains vmcnt before s_barrier

    short8 af[4], bf[4];
#pragma unroll
    for (int mi = 0; mi < 4; mi++)
      af[mi] = *(const short8*)&As[(wm * 64 + mi * 16 + lr) * 32 + quad * 8];
#pragma unroll
    for (int ni = 0; ni < 4; ni++)
      bf[ni] = *(const short8*)&Bs[(wn * 64 + ni * 16 + lr) * 32 + quad * 8];
#pragma unroll
    for (int mi = 0; mi < 4; mi++)
#pragma unroll
      for (int ni = 0; ni < 4; ni++)
        acc[mi][ni] = __builtin_amdgcn_mfma_f32_16x16x32_bf16(af[mi], bf[ni], acc[mi][ni], 0, 0, 0);
    __syncthreads();
  }

#pragma unroll
  for (int mi = 0; mi < 4; mi++) {
#pragma unroll
    for (int r = 0; r < 4; r++) {
      int row = row0 + wm * 64 + mi * 16 + quad * 4 + r;
      float* Crow = C + (size_t)row * 4096 + col0 + wn * 64;
#pragma unroll
      for (int ni = 0; ni < 4; ni++) {
        int c = ni * 16 + lr;
        int gc = col0 + wn * 64 + c;
        float v = acc[mi][ni][r];
        if ((gc & 63) == (gc >> 6)) v += 1.0f;  // + I(o==i)
        Crow[c] = v;
      }
    }
  }
}

extern "C" void kernel_launch(void* const* d_in, const int* in_sizes, int n_in,
                              void* d_out, int out_size, void* d_ws, size_t ws_size,
                              hipStream_t stream) {
  const float* x = (const float*)d_in[0];
  const float* y = (const float*)d_in[1];
  const float* W1 = (const float*)d_in[2];
  const float* b1 = (const float*)d_in[3];
  const float* W2 = (const float*)d_in[4];
  const float* b2 = (const float*)d_in[5];
  const float* Wb1 = (const float*)d_in[6];
  const float* bb1 = (const float*)d_in[7];
  const float* Wb2 = (const float*)d_in[8];
  const float* bb2 = (const float*)d_in[9];
  const float* Wc1 = (const float*)d_in[10];
  const float* bc1 = (const float*)d_in[11];
  const float* Wc2 = (const float*)d_in[12];
  const float* bc2 = (const float*)d_in[13];
  const float* meanp = (const float*)d_in[14];
  const float* varp = (const float*)d_in[15];

  float* z = (float*)d_out;
  float* jac = z + (size_t)NS * NXD;

  char* ws = (char*)d_ws;
  __hip_bfloat16* W12T = (__hip_bfloat16*)ws;                        // 4 MB
  __hip_bfloat16* Mb = (__hip_bfloat16*)(ws + (4ull << 20));         // 32 MB
  float* wts = (float*)(ws + (36ull << 20));                         // 2 MB

  prep_w12<<<dim3(8192), dim3(256), 0, stream>>>(W1, W2, W12T);
  branch_kernel<<<dim3(128), dim3(256), 0, stream>>>(
      x, y, b2, Wb1, bb1, Wb2, bb2, Wc1, bc1, Wc2, bc2, meanp, varp, wts, z);
  moe_kernel<<<dim3(4096), dim3(256), 0, stream>>>(x, W1, b1, W2, wts, Mb, z);
  jac_gemm<<<dim3(32, 256), dim3(256), 0, stream>>>(Mb, W12T, jac);
}